// Round 2
// baseline (35.120 us; speedup 1.0000x reference)
//
#include <hip/hip_runtime.h>

// LIF scan, x (B=32,G=4,T=512,C=256) f32. N=B*G=128 sequences, C=256 channels
// -> 32768 independent chains, one per thread; T is sequential (nonlinear
// recurrence). Memory-bound: 67 MB read + 67 MB write, roofline ~21 us.
//
// Structure: 512 blocks x 64 threads (1 wave). Each block owns 64 channels of
// one sequence. x is staged in 32-step tiles (8 KB) into a 4-deep LDS ring via
// global_load_lds_dwordx4 (wave-linear LDS dest), consumed with counted
// s_waitcnt vmcnt(N) (T4: never drain to 0). Outputs are transposed through a
// 1 KB LDS buffer into global_store_dwordx4, cutting store instrs 4x and
// keeping them out of the load pipeline's vmcnt budget.

constexpr int T_STEPS = 512;
constexpr int CCH     = 256;
constexpr int NSEQ    = 128;            // B*G
constexpr int TILE    = 32;             // timesteps per tile
constexpr int NTILES  = T_STEPS / TILE; // 16
constexpr int CB      = 64;             // channels per block

__device__ __forceinline__ void issue_tile(const float* __restrict__ gx_lane,
                                           int t0, float* lds_base) {
    // 8 x global_load_lds_dwordx4: sub-block s covers timesteps t0+4s..t0+4s+3.
    // lane i: t = t0+4s+(i>>4), c = 4*(i&15); LDS dest = base + s*1KiB + lane*16B
    // which is exactly the linear [t_local][c_local] layout.
#pragma unroll
    for (int s = 0; s < 8; ++s) {
        __builtin_amdgcn_global_load_lds(
            (const __attribute__((address_space(1))) void*)(gx_lane + (size_t)(t0 + 4 * s) * CCH),
            (__attribute__((address_space(3))) void*)(lds_base + s * 4 * CB),
            16, 0, 0);
    }
}

template <int WN>
__device__ __forceinline__ void consume_tile(const float* xb, float* ob,
                                             float* __restrict__ go_lane, int t0,
                                             float w, float a,
                                             float& Vm, float& R, int lane) {
#pragma clang fp contract(off)
    // Wait until this tile's 8 loads (the oldest outstanding vmem ops) are
    // done: WN = exact count of vmem ops issued after them (loads + x4 stores).
    asm volatile("s_waitcnt vmcnt(%0)" ::"n"(WN) : "memory");
#pragma unroll
    for (int j = 0; j < TILE; ++j) {
        const float xt = xb[j * CB + lane];   // ds_read_b32, conflict-free

        // R = heaviside(Vm-1)*1 + heaviside(R-1)*(R-1)   (old Vm, old R)
        const float spike = (Vm - 1.0f >= 0.0f) ? 1.0f : 0.0f;
        const float rdec  = (R  - 1.0f >= 0.0f) ? (R - 1.0f) : 0.0f;
        R = spike + rdec;

        // Vm = (w*xt + (1-wl)*Vm) * heaviside(-R)  -- exact numpy op order
        const float v = (w * xt) + (a * Vm);
        Vm = (-R >= 0.0f) ? v : 0.0f;

        ob[(j & 3) * CB + lane] = Vm;         // stage for transposed x4 store
        if ((j & 3) == 3) {
            // lane i stores t = t0+(j-3)+(i>>4), channels 4*(i&15)..+3
            const float4 vv = *(const float4*)&ob[(lane >> 4) * CB + 4 * (lane & 15)];
            *(float4*)(go_lane + (size_t)(t0 + (j - 3)) * CCH) = vv;
        }
    }
}

__global__ __launch_bounds__(64, 1) void lif_kernel(
    const float* __restrict__ x,
    const float* __restrict__ w_input,
    const float* __restrict__ w_leak,
    float* __restrict__ out)
{
    __shared__ float xbuf[4 * TILE * CB];   // 32 KB ring, 4 tiles
    __shared__ float obuf[4 * CB];          // 1 KB store-transpose staging

    const int lane = threadIdx.x;
    const int n  = blockIdx.x >> 2;
    const int cb = (blockIdx.x & 3) << 6;

    const int ch = cb + lane;               // this thread's channel
    const float w = w_input[ch];
    const float a = 1.0f - w_leak[ch];

    // per-lane global base for x4 tile traffic: row (lane>>4), col 4*(lane&15)
    const float* gx = x   + (size_t)n * T_STEPS * CCH + cb + (lane >> 4) * CCH + 4 * (lane & 15);
    float*       go = out + (size_t)n * T_STEPS * CCH + cb + (lane >> 4) * CCH + 4 * (lane & 15);

    // Prologue: fill the ring (tiles 0..3, 32 loads in flight)
    issue_tile(gx, 0 * TILE, &xbuf[0 * TILE * CB]);
    issue_tile(gx, 1 * TILE, &xbuf[1 * TILE * CB]);
    issue_tile(gx, 2 * TILE, &xbuf[2 * TILE * CB]);
    issue_tile(gx, 3 * TILE, &xbuf[3 * TILE * CB]);

    float Vm = 0.0f, R = 0.0f;

    // Exact after-counts (8 ops per L/S group):
    // T=0: L1,L2,L3 = 24          T=1: L2,L3,S0,L4 = 32
    // T=2: L3,S0,L4,S1,L5 = 40    T=3..12: 3S+3L = 48
    // T=13: 40   T=14: 32   T=15: 24
    consume_tile<24>(&xbuf[0 * TILE * CB], obuf, go, 0 * TILE, w, a, Vm, R, lane);
    issue_tile(gx, 4 * TILE, &xbuf[0 * TILE * CB]);
    consume_tile<32>(&xbuf[1 * TILE * CB], obuf, go, 1 * TILE, w, a, Vm, R, lane);
    issue_tile(gx, 5 * TILE, &xbuf[1 * TILE * CB]);
    consume_tile<40>(&xbuf[2 * TILE * CB], obuf, go, 2 * TILE, w, a, Vm, R, lane);
    issue_tile(gx, 6 * TILE, &xbuf[2 * TILE * CB]);

    for (int T = 3; T <= 12; ++T) {
        consume_tile<48>(&xbuf[(T & 3) * TILE * CB], obuf, go, T * TILE, w, a, Vm, R, lane);
        if (T + 4 < NTILES)
            issue_tile(gx, (T + 4) * TILE, &xbuf[(T & 3) * TILE * CB]);
    }

    consume_tile<40>(&xbuf[(13 & 3) * TILE * CB], obuf, go, 13 * TILE, w, a, Vm, R, lane);
    consume_tile<32>(&xbuf[(14 & 3) * TILE * CB], obuf, go, 14 * TILE, w, a, Vm, R, lane);
    consume_tile<24>(&xbuf[(15 & 3) * TILE * CB], obuf, go, 15 * TILE, w, a, Vm, R, lane);
}

extern "C" void kernel_launch(void* const* d_in, const int* in_sizes, int n_in,
                              void* d_out, int out_size, void* d_ws, size_t ws_size,
                              hipStream_t stream) {
    const float* x       = (const float*)d_in[0];
    const float* w_input = (const float*)d_in[1];
    const float* w_leak  = (const float*)d_in[2];
    float* out = (float*)d_out;

    dim3 grid(NSEQ * (CCH / CB));   // 512 blocks
    dim3 block(64);
    hipLaunchKernelGGL(lif_kernel, grid, block, 0, stream,
                       x, w_input, w_leak, out);
}

// Round 3
// 30.761 us; speedup vs baseline: 1.1417x; 1.1417x over previous
//
#include <hip/hip_runtime.h>

// LIF scan, x (B=32,G=4,T=512,C=256) f32 -> 32768 independent chains (one per
// thread), T sequential. Memory-bound: 67 MB read + 67 MB write, floor ~21 us.
//
// R3 design:
//  - Simplified exact recurrence: with V_thresh=T_ref=1, R is always {0,1},
//    so  Vm' = (Vm >= 1) ? 0 : (w*xt + a*Vm).  Bit-identical to the full form
//    (same op order, contraction off), 5 VALU/step, 3-op dependent chain.
//  - Register prefetch ring (D=32) for x: proven best load path (round 1).
//  - LDS store-transpose: stage 4 steps x 64 ch, then 8x global_store_dwordx4
//    per 32-step tile (vs 32 scalar stores) -> load->use vmcnt distance ~40
//    (round 1 sat at the 63 cap, forcing conservative waits).
//  - XCD-coherent swizzle: the 4 channel-slice blocks of sequence n share
//    XCD n%8, so each XCD's HBM stream is row-contiguous (page locality).

constexpr int T_STEPS = 512;
constexpr int CCH     = 256;
constexpr int NSEQ    = 128;   // B*G
constexpr int D       = 32;    // prefetch depth / tile (T_STEPS % D == 0)
constexpr int CB      = 64;    // channels per block

__global__ __launch_bounds__(64, 1) void lif_kernel(
    const float* __restrict__ x,
    const float* __restrict__ w_input,
    const float* __restrict__ w_leak,
    float* __restrict__ out)
{
#pragma clang fp contract(off)
    __shared__ float obuf[4 * CB];          // 1 KB store-transpose staging

    const int lane = threadIdx.x;
    const int b    = blockIdx.x;
    // swizzle: b = (n%8) + 8*(4*(n/8) + cb_idx)  ->  XCD(b%8) == n%8
    const int n  = (b & 7) + ((b >> 5) << 3);
    const int cb = ((b >> 3) & 3) << 6;

    const int ch = cb + lane;
    const float w = w_input[ch];
    const float a = 1.0f - w_leak[ch];

    const float* xp = x + (size_t)n * T_STEPS * CCH + ch;     // scalar load base
    // x4 store base: lane i covers t-offset (i>>4), channels 4*(i&15)..+3
    float* go = out + (size_t)n * T_STEPS * CCH + cb + (lane >> 4) * CCH + 4 * (lane & 15);

    // Prime the ring: x[0..D-1]
    float buf[D];
#pragma unroll
    for (int d0 = 0; d0 < D; ++d0) buf[d0] = xp[(size_t)d0 * CCH];

    float Vm = 0.0f;

    // Main loop: consume buf[k] (loaded D steps ago), refill with x[t+D].
    for (int t0 = 0; t0 < T_STEPS - D; t0 += D) {
#pragma unroll
        for (int k = 0; k < D; ++k) {
            const float xt = buf[k];
            buf[k] = xp[(size_t)(t0 + D + k) * CCH];

            // exact numpy op order: mul, mul, add (no FMA), then spike gate
            const float v = (w * xt) + (a * Vm);
            Vm = (Vm - 1.0f >= 0.0f) ? 0.0f : v;

            obuf[(k & 3) * CB + lane] = Vm;   // stage for transposed x4 store
            if ((k & 3) == 3) {
                const float4 vv = *(const float4*)&obuf[(lane >> 4) * CB + 4 * (lane & 15)];
                *(float4*)(go + (size_t)(t0 + (k - 3)) * CCH) = vv;
            }
        }
    }

    // Tail: last D steps, ring already holds x[T-D .. T-1]
#pragma unroll
    for (int k = 0; k < D; ++k) {
        const float xt = buf[k];
        const float v = (w * xt) + (a * Vm);
        Vm = (Vm - 1.0f >= 0.0f) ? 0.0f : v;

        obuf[(k & 3) * CB + lane] = Vm;
        if ((k & 3) == 3) {
            const float4 vv = *(const float4*)&obuf[(lane >> 4) * CB + 4 * (lane & 15)];
            *(float4*)(go + (size_t)(T_STEPS - D + (k - 3)) * CCH) = vv;
        }
    }
}

extern "C" void kernel_launch(void* const* d_in, const int* in_sizes, int n_in,
                              void* d_out, int out_size, void* d_ws, size_t ws_size,
                              hipStream_t stream) {
    const float* x       = (const float*)d_in[0];
    const float* w_input = (const float*)d_in[1];
    const float* w_leak  = (const float*)d_in[2];
    float* out = (float*)d_out;

    dim3 grid(NSEQ * (CCH / CB));   // 512 blocks
    dim3 block(64);
    hipLaunchKernelGGL(lif_kernel, grid, block, 0, stream,
                       x, w_input, w_leak, out);
}